// Round 3
// baseline (446.380 us; speedup 1.0000x reference)
//
#include <hip/hip_runtime.h>
#include <hip/hip_bf16.h>

// Edges GNN message MLP: per-edge RBF(100) + gather h[src],h[dst] (64+64)
// -> Linear(228->128) -> SiLU -> Linear(128->64).
// R6 design: persistent pipelined waves. Weights stay LDS-resident (R5), but
// blocks are persistent (grid=256) and each wave grid-strides over ~12 chunks
// of 32 edges with a 1-deep software pipeline: next chunk's index loads are
// issued at iteration start and its 8 h-gathers are issued the moment the
// current chunk's A-fragments are consumed, so the ~1200cy random-gather
// chain hides under transpose+layer2+store+RBF of the current chunk.
// Occupancy stays 2 waves/SIMD (148KB LDS); the bet is ILP replaces TLP.

#define FEAT     64
#define NMU      100
#define K1_REAL  228
#define HID      128
#define ODIM     64
#define K2       128
#define WEDGES   32        // edges per chunk
#define NWAVES   8
#define LDH2     136       // bf16 leading dim of per-wave H tile (16B-aligned rows)
#define HN8      400000    // (50000*64)/8 bf16x8 groups in h
#define GRID     256       // persistent blocks

typedef __bf16 bf16x8 __attribute__((ext_vector_type(8)));
typedef float  fx4    __attribute__((ext_vector_type(4)));

// Pack W1 [128 x 228] and W2 [64 x 128] fp32 -> bf16 MFMA B-fragment order.
// B1[((kk*4+q)*128 + n)*8 + j] = W1[n][kk*32 + q*8 + j]  (0 if k >= 228)
// B2[((kk*4+q)*64  + n)*8 + j] = W2[n][kk*32 + q*8 + j]
__global__ void pack_w(const float* __restrict__ W1, const float* __restrict__ W2,
                       __bf16* __restrict__ B1, __bf16* __restrict__ B2) {
    int i = blockIdx.x * 256 + threadIdx.x;     // 0..40959
    if (i < 32768) {
        int j  = i & 7;
        int n  = (i >> 3) & 127;
        int qk = i >> 10;
        int k  = (qk >> 2) * 32 + (qk & 3) * 8 + j;
        float v = (k < K1_REAL) ? W1[n * K1_REAL + k] : 0.0f;
        B1[i] = (__bf16)v;
    } else {
        int t = i - 32768;
        int j  = t & 7;
        int n  = (t >> 3) & 63;
        int qk = t >> 9;
        int k  = (qk >> 2) * 32 + (qk & 3) * 8 + j;
        B2[t] = (__bf16)W2[n * K2 + k];
    }
}

// Convert h [50000 x 64] fp32 -> bf16 table (row-major, same layout).
__global__ void pack_h(const float* __restrict__ h, __bf16* __restrict__ hb) {
    int i = blockIdx.x * 256 + threadIdx.x;     // one bf16x8 group each
    if (i >= HN8) return;
    const float4* p = (const float4*)h + (size_t)i * 2;
    float4 v0 = p[0];
    float4 v1 = p[1];
    bf16x8 b = { (__bf16)v0.x, (__bf16)v0.y, (__bf16)v0.z, (__bf16)v0.w,
                 (__bf16)v1.x, (__bf16)v1.y, (__bf16)v1.z, (__bf16)v1.w };
    ((bf16x8*)hb)[i] = b;
}

__device__ __forceinline__ bf16x8 hfrag_f32(const float* __restrict__ h, int node, int cb) {
    const float4* p = (const float4*)(h + (size_t)node * FEAT + cb);
    float4 v0 = p[0];
    float4 v1 = p[1];
    bf16x8 a = { (__bf16)v0.x, (__bf16)v0.y, (__bf16)v0.z, (__bf16)v0.w,
                 (__bf16)v1.x, (__bf16)v1.y, (__bf16)v1.z, (__bf16)v1.w };
    return a;
}

template<bool HB16>
__global__ __launch_bounds__(512, 2)
void edges_fused(const float* __restrict__ h,
                 const __bf16* __restrict__ hb,
                 const int*   __restrict__ src,
                 const int*   __restrict__ dst,
                 const float* __restrict__ enorm,
                 const float* __restrict__ mu,
                 const __bf16* __restrict__ B1,
                 const __bf16* __restrict__ B2,
                 float* __restrict__ out,
                 int nchunk) {
    // 64K + 16K + 68K = 148 KB static LDS -> 1 block/CU.
    __shared__ __bf16 B1s[32768];
    __shared__ __bf16 B2s[8192];
    __shared__ __bf16 Hs[NWAVES * WEDGES * LDH2];

    const int tid  = threadIdx.x;
    const int w    = tid >> 6;
    const int lane = tid & 63;
    const int ln   = lane & 15;
    const int q    = lane >> 4;
    const int wid  = blockIdx.x * NWAVES + w;       // global wave id
    const int NW   = gridDim.x * NWAVES;            // total waves (2048)

    // ---- Prologue: first chunk's indices (issue before staging) ----
    int c = wid;
    int nsA[2], ndA[2];
    float dvA[2];
#pragma unroll
    for (int mt = 0; mt < 2; ++mt) {
        int e = c * WEDGES + mt * 16 + ln;
        nsA[mt] = src[e];
        ndA[mt] = dst[e];
        dvA[mt] = enorm[e];
    }

    // ---- Stage weights into LDS (once per persistent block) ----
    {
        const bf16x8* gB1 = (const bf16x8*)B1;
        const bf16x8* gB2 = (const bf16x8*)B2;
        bf16x8* sB1 = (bf16x8*)B1s;
        bf16x8* sB2 = (bf16x8*)B2s;
#pragma unroll
        for (int it = 0; it < 8; ++it) {   // 4096 groups / 512 threads
            int g = it * 512 + tid;
            sB1[g] = gB1[g];
        }
#pragma unroll
        for (int it = 0; it < 2; ++it) {   // 1024 groups / 512 threads
            int g = it * 512 + tid;
            sB2[g] = gB2[g];
        }
    }

    // ---- Prologue gathers (overlap the staging + barrier wait) ----
    bf16x8 ag[4][2];     // [kk][mt] gathered A-fragments
#pragma unroll
    for (int kk = 0; kk < 4; ++kk) {
        const int cb = (kk & 1) * 32 + q * 8;
#pragma unroll
        for (int mt = 0; mt < 2; ++mt) {
            int node = (kk < 2) ? nsA[mt] : ndA[mt];
            if constexpr (HB16)
                ag[kk][mt] = *(const bf16x8*)(hb + (size_t)node * FEAT + cb);
            else
                ag[kk][mt] = hfrag_f32(h, node, cb);
        }
    }

    __syncthreads();

    __bf16* Hw = &Hs[w * WEDGES * LDH2];

    while (c < nchunk) {
        const int cn = c + NW;
        const bool haveN = (cn < nchunk);

        // ---- Issue next chunk's index loads early ----
        int nsB[2], ndB[2];
        float dvB[2];
        if (haveN) {
#pragma unroll
            for (int mt = 0; mt < 2; ++mt) {
                int e = cn * WEDGES + mt * 16 + ln;
                nsB[mt] = src[e];
                ndB[mt] = dst[e];
                dvB[mt] = enorm[e];
            }
        }

        // ---- Layer 1: [32 x 256pad] @ [256 x 128] ----
        fx4 acc1[2][8];
#pragma unroll
        for (int mt = 0; mt < 2; ++mt)
#pragma unroll
            for (int nt = 0; nt < 8; ++nt)
                acc1[mt][nt] = (fx4){0.f, 0.f, 0.f, 0.f};

        // kk = 4..6 first (RBF, pure VALU/trans) to give the in-flight
        // gathers maximum slack before kk=0 consumes ag.
#pragma unroll
        for (int kk = 4; kk < 7; ++kk) {
            const int c0 = (kk - 4) * 32 + q * 8;
            float4 m0 = *(const float4*)(mu + c0);
            float4 m1 = *(const float4*)(mu + c0 + 4);
            bf16x8 a[2];
#pragma unroll
            for (int mt = 0; mt < 2; ++mt) {
                float d = dvA[mt];
                float t0 = m0.x - d, t1 = m0.y - d, t2 = m0.z - d, t3 = m0.w - d;
                float t4 = m1.x - d, t5 = m1.y - d, t6 = m1.z - d, t7 = m1.w - d;
                a[mt] = (bf16x8){ (__bf16)__expf(-10.f * t0 * t0), (__bf16)__expf(-10.f * t1 * t1),
                                  (__bf16)__expf(-10.f * t2 * t2), (__bf16)__expf(-10.f * t3 * t3),
                                  (__bf16)__expf(-10.f * t4 * t4), (__bf16)__expf(-10.f * t5 * t5),
                                  (__bf16)__expf(-10.f * t6 * t6), (__bf16)__expf(-10.f * t7 * t7) };
            }
#pragma unroll
            for (int nt = 0; nt < 8; ++nt) {
                bf16x8 b = *(const bf16x8*)&B1s[(((kk * 4 + q) * 128) + nt * 16 + ln) * 8];
                acc1[0][nt] = __builtin_amdgcn_mfma_f32_16x16x32_bf16(a[0], b, acc1[0][nt], 0, 0, 0);
                acc1[1][nt] = __builtin_amdgcn_mfma_f32_16x16x32_bf16(a[1], b, acc1[1][nt], 0, 0, 0);
            }
        }
        // kk = 7: only q==0 lanes carry real values (RBF cols 96..99).
        {
            float4 m7 = *(const float4*)(mu + 96);
            const __bf16 zz = (__bf16)0.0f;
            const bool qz = (q == 0);
            bf16x8 a[2];
#pragma unroll
            for (int mt = 0; mt < 2; ++mt) {
                float d = dvA[mt];
                float t0 = m7.x - d, t1 = m7.y - d, t2 = m7.z - d, t3 = m7.w - d;
                a[mt] = (bf16x8){ qz ? (__bf16)__expf(-10.f * t0 * t0) : zz,
                                  qz ? (__bf16)__expf(-10.f * t1 * t1) : zz,
                                  qz ? (__bf16)__expf(-10.f * t2 * t2) : zz,
                                  qz ? (__bf16)__expf(-10.f * t3 * t3) : zz,
                                  zz, zz, zz, zz };
            }
#pragma unroll
            for (int nt = 0; nt < 8; ++nt) {
                bf16x8 b = *(const bf16x8*)&B1s[(((7 * 4 + q) * 128) + nt * 16 + ln) * 8];
                acc1[0][nt] = __builtin_amdgcn_mfma_f32_16x16x32_bf16(a[0], b, acc1[0][nt], 0, 0, 0);
                acc1[1][nt] = __builtin_amdgcn_mfma_f32_16x16x32_bf16(a[1], b, acc1[1][nt], 0, 0, 0);
            }
        }
        // kk = 0..3: gathered node features (registers, loaded last iteration)
#pragma unroll
        for (int kk = 0; kk < 4; ++kk) {
#pragma unroll
            for (int nt = 0; nt < 8; ++nt) {
                bf16x8 b = *(const bf16x8*)&B1s[(((kk * 4 + q) * 128) + nt * 16 + ln) * 8];
                acc1[0][nt] = __builtin_amdgcn_mfma_f32_16x16x32_bf16(ag[kk][0], b, acc1[0][nt], 0, 0, 0);
                acc1[1][nt] = __builtin_amdgcn_mfma_f32_16x16x32_bf16(ag[kk][1], b, acc1[1][nt], 0, 0, 0);
            }
        }

        // ---- Issue next chunk's gathers now that ag is dead ----
        if (haveN) {
#pragma unroll
            for (int kk = 0; kk < 4; ++kk) {
                const int cb = (kk & 1) * 32 + q * 8;
#pragma unroll
                for (int mt = 0; mt < 2; ++mt) {
                    int node = (kk < 2) ? nsB[mt] : ndB[mt];
                    if constexpr (HB16)
                        ag[kk][mt] = *(const bf16x8*)(hb + (size_t)node * FEAT + cb);
                    else
                        ag[kk][mt] = hfrag_f32(h, node, cb);
                }
            }
        }

        // ---- SiLU + wave-private transpose (C-layout -> row-major bf16) ----
#pragma unroll
        for (int mt = 0; mt < 2; ++mt)
#pragma unroll
            for (int nt = 0; nt < 8; ++nt)
#pragma unroll
                for (int r = 0; r < 4; ++r) {
                    float z = acc1[mt][nt][r];
                    float s = z * __builtin_amdgcn_rcpf(1.0f + __expf(-z));
                    Hw[(mt * 16 + q * 4 + r) * LDH2 + nt * 16 + ln] = (__bf16)s;
                }
        // Same-wave LDS RAW/WAR: DS pipe is in-order per wave; compiler sees
        // aliasing through Hs and keeps program order.

        // ---- Layer 2: [32 x 128] @ [128 x 64] ----
        fx4 acc2[2][4];
#pragma unroll
        for (int mt = 0; mt < 2; ++mt)
#pragma unroll
            for (int nt = 0; nt < 4; ++nt)
                acc2[mt][nt] = (fx4){0.f, 0.f, 0.f, 0.f};

#pragma unroll
        for (int kk = 0; kk < 4; ++kk) {
            bf16x8 a2[2];
#pragma unroll
            for (int mt = 0; mt < 2; ++mt)
                a2[mt] = *(const bf16x8*)&Hw[(mt * 16 + ln) * LDH2 + kk * 32 + q * 8];
#pragma unroll
            for (int nt = 0; nt < 4; ++nt) {
                bf16x8 b2 = *(const bf16x8*)&B2s[(((kk * 4 + q) * 64) + nt * 16 + ln) * 8];
                acc2[0][nt] = __builtin_amdgcn_mfma_f32_16x16x32_bf16(a2[0], b2, acc2[0][nt], 0, 0, 0);
                acc2[1][nt] = __builtin_amdgcn_mfma_f32_16x16x32_bf16(a2[1], b2, acc2[1][nt], 0, 0, 0);
            }
        }

        // ---- Store current chunk ----
        const int g0 = c * WEDGES;
#pragma unroll
        for (int mt = 0; mt < 2; ++mt)
#pragma unroll
            for (int nt = 0; nt < 4; ++nt)
#pragma unroll
                for (int r = 0; r < 4; ++r)
                    out[(size_t)(g0 + mt * 16 + q * 4 + r) * ODIM + nt * 16 + ln] = acc2[mt][nt][r];

        // ---- Rotate ----
        dvA[0] = dvB[0];
        dvA[1] = dvB[1];
        c = cn;
    }
}

extern "C" void kernel_launch(void* const* d_in, const int* in_sizes, int n_in,
                              void* d_out, int out_size, void* d_ws, size_t ws_size,
                              hipStream_t stream) {
    const float* h   = (const float*)d_in[0];
    const int*   src = (const int*)d_in[1];
    const int*   dst = (const int*)d_in[2];
    const float* en  = (const float*)d_in[3];
    const float* mu  = (const float*)d_in[4];
    const float* W1  = (const float*)d_in[5];
    const float* W2  = (const float*)d_in[6];

    __bf16* B1 = (__bf16*)d_ws;                          // 32768 bf16 = 64 KB
    __bf16* B2 = (__bf16*)((char*)d_ws + 65536);         // 8192 bf16  = 16 KB
    __bf16* HB = (__bf16*)((char*)d_ws + 81920);         // 3.2M bf16  = 6.4 MB

    const size_t ws_needed = 81920 + (size_t)HN8 * 8 * sizeof(__bf16);
    const bool   use_hb    = ws_size >= ws_needed;

    pack_w<<<160, 256, 0, stream>>>(W1, W2, B1, B2);

    const int E = in_sizes[1];                 // 800000
    const int nchunk = E / WEDGES;             // 25000

    if (use_hb) {
        pack_h<<<(HN8 + 255) / 256, 256, 0, stream>>>(h, HB);
        edges_fused<true><<<GRID, 512, 0, stream>>>(h, HB, src, dst, en, mu, B1, B2, (float*)d_out, nchunk);
    } else {
        edges_fused<false><<<GRID, 512, 0, stream>>>(h, nullptr, src, dst, en, mu, B1, B2, (float*)d_out, nchunk);
    }
}

// Round 4
// 437.509 us; speedup vs baseline: 1.0203x; 1.0203x over previous
//
#include <hip/hip_runtime.h>
#include <hip/hip_bf16.h>

// Edges GNN message MLP: per-edge RBF(100) + gather h[src],h[dst] (64+64)
// -> Linear(228->128) -> SiLU -> Linear(128->64).
// R7 design: R5 structure + persistent blocks, register-lean.
// Weights staged to LDS ONCE per persistent block (grid=256, ~12 chunks/wave)
// instead of once per 256 edges (R5: 3125 stages). Unlike R6 (which spilled:
// +96MB scratch writes, +600MB scratch fetch, 128 VGPR), NO cross-iteration
// gather prefetch: per iteration the 8 h-gathers are issued first and
// consumed after the RBF slabs (~700cy of VALU+MFMA) -- within-iteration
// overlap only. Only loop-carried state: next chunk's 6 index scalars.

#define FEAT     64
#define NMU      100
#define K1_REAL  228
#define HID      128
#define ODIM     64
#define K2       128
#define WEDGES   32        // edges per chunk
#define NWAVES   8
#define LDH2     136       // bf16 leading dim of per-wave H tile (16B-aligned rows)
#define HN8      400000    // (50000*64)/8 bf16x8 groups in h
#define GRID     256       // persistent blocks (1/CU, LDS-limited)

typedef __bf16 bf16x8 __attribute__((ext_vector_type(8)));
typedef float  fx4    __attribute__((ext_vector_type(4)));

// Pack W1 [128 x 228] and W2 [64 x 128] fp32 -> bf16 MFMA B-fragment order.
// B1[((kk*4+q)*128 + n)*8 + j] = W1[n][kk*32 + q*8 + j]  (0 if k >= 228)
// B2[((kk*4+q)*64  + n)*8 + j] = W2[n][kk*32 + q*8 + j]
__global__ void pack_w(const float* __restrict__ W1, const float* __restrict__ W2,
                       __bf16* __restrict__ B1, __bf16* __restrict__ B2) {
    int i = blockIdx.x * 256 + threadIdx.x;     // 0..40959
    if (i < 32768) {
        int j  = i & 7;
        int n  = (i >> 3) & 127;
        int qk = i >> 10;
        int k  = (qk >> 2) * 32 + (qk & 3) * 8 + j;
        float v = (k < K1_REAL) ? W1[n * K1_REAL + k] : 0.0f;
        B1[i] = (__bf16)v;
    } else {
        int t = i - 32768;
        int j  = t & 7;
        int n  = (t >> 3) & 63;
        int qk = t >> 9;
        int k  = (qk >> 2) * 32 + (qk & 3) * 8 + j;
        B2[t] = (__bf16)W2[n * K2 + k];
    }
}

// Convert h [50000 x 64] fp32 -> bf16 table (row-major, same layout).
__global__ void pack_h(const float* __restrict__ h, __bf16* __restrict__ hb) {
    int i = blockIdx.x * 256 + threadIdx.x;     // one bf16x8 group each
    if (i >= HN8) return;
    const float4* p = (const float4*)h + (size_t)i * 2;
    float4 v0 = p[0];
    float4 v1 = p[1];
    bf16x8 b = { (__bf16)v0.x, (__bf16)v0.y, (__bf16)v0.z, (__bf16)v0.w,
                 (__bf16)v1.x, (__bf16)v1.y, (__bf16)v1.z, (__bf16)v1.w };
    ((bf16x8*)hb)[i] = b;
}

__device__ __forceinline__ bf16x8 hfrag_f32(const float* __restrict__ h, int node, int cb) {
    const float4* p = (const float4*)(h + (size_t)node * FEAT + cb);
    float4 v0 = p[0];
    float4 v1 = p[1];
    bf16x8 a = { (__bf16)v0.x, (__bf16)v0.y, (__bf16)v0.z, (__bf16)v0.w,
                 (__bf16)v1.x, (__bf16)v1.y, (__bf16)v1.z, (__bf16)v1.w };
    return a;
}

template<bool HB16>
__global__ __launch_bounds__(512, 2)
void edges_fused(const float* __restrict__ h,
                 const __bf16* __restrict__ hb,
                 const int*   __restrict__ src,
                 const int*   __restrict__ dst,
                 const float* __restrict__ enorm,
                 const float* __restrict__ mu,
                 const __bf16* __restrict__ B1,
                 const __bf16* __restrict__ B2,
                 float* __restrict__ out,
                 int nchunk) {
    // 64K + 16K + 68K = 148 KB static LDS -> 1 block/CU.
    __shared__ __bf16 B1s[32768];
    __shared__ __bf16 B2s[8192];
    __shared__ __bf16 Hs[NWAVES * WEDGES * LDH2];

    const int tid  = threadIdx.x;
    const int w    = tid >> 6;
    const int lane = tid & 63;
    const int ln   = lane & 15;
    const int q    = lane >> 4;
    const int wid  = blockIdx.x * NWAVES + w;       // global wave id
    const int NW   = gridDim.x * NWAVES;            // total waves (2048)

    // ---- First chunk's indices (issue before staging so they overlap) ----
    int c = wid;
    int nsA[2], ndA[2];
    float dvA[2];
    if (c < nchunk) {
#pragma unroll
        for (int mt = 0; mt < 2; ++mt) {
            int e = c * WEDGES + mt * 16 + ln;
            nsA[mt] = src[e];
            ndA[mt] = dst[e];
            dvA[mt] = enorm[e];
        }
    }

    // ---- Stage weights into LDS (once per persistent block) ----
    {
        const bf16x8* gB1 = (const bf16x8*)B1;
        const bf16x8* gB2 = (const bf16x8*)B2;
        bf16x8* sB1 = (bf16x8*)B1s;
        bf16x8* sB2 = (bf16x8*)B2s;
#pragma unroll
        for (int it = 0; it < 8; ++it) {   // 4096 groups / 512 threads
            int g = it * 512 + tid;
            sB1[g] = gB1[g];
        }
#pragma unroll
        for (int it = 0; it < 2; ++it) {   // 1024 groups / 512 threads
            int g = it * 512 + tid;
            sB2[g] = gB2[g];
        }
    }
    __syncthreads();

    __bf16* Hw = &Hs[w * WEDGES * LDH2];

    while (c < nchunk) {
        const int cn = c + NW;
        const bool haveN = (cn < nchunk);

        // ---- Issue this chunk's 8 gathers FIRST (consumed after RBF) ----
        bf16x8 ag[4][2];
#pragma unroll
        for (int kk = 0; kk < 4; ++kk) {
            const int cb = (kk & 1) * 32 + q * 8;
#pragma unroll
            for (int mt = 0; mt < 2; ++mt) {
                int node = (kk < 2) ? nsA[mt] : ndA[mt];
                if constexpr (HB16)
                    ag[kk][mt] = *(const bf16x8*)(hb + (size_t)node * FEAT + cb);
                else
                    ag[kk][mt] = hfrag_f32(h, node, cb);
            }
        }

        // ---- Issue next chunk's index loads (6 regs loop-carried) ----
        int nsB[2], ndB[2];
        float dvB[2];
        if (haveN) {
#pragma unroll
            for (int mt = 0; mt < 2; ++mt) {
                int e = cn * WEDGES + mt * 16 + ln;
                nsB[mt] = src[e];
                ndB[mt] = dst[e];
                dvB[mt] = enorm[e];
            }
        }

        // ---- Layer 1: [32 x 256pad] @ [256 x 128] ----
        fx4 acc1[2][8];
#pragma unroll
        for (int mt = 0; mt < 2; ++mt)
#pragma unroll
            for (int nt = 0; nt < 8; ++nt)
                acc1[mt][nt] = (fx4){0.f, 0.f, 0.f, 0.f};

        // kk = 4..6 first (RBF, pure VALU+MFMA) -- gives the in-flight
        // gathers ~700cy of slack before kk=0 consumes ag.
#pragma unroll
        for (int kk = 4; kk < 7; ++kk) {
            const int c0 = (kk - 4) * 32 + q * 8;
            float4 m0 = *(const float4*)(mu + c0);
            float4 m1 = *(const float4*)(mu + c0 + 4);
            bf16x8 a[2];
#pragma unroll
            for (int mt = 0; mt < 2; ++mt) {
                float d = dvA[mt];
                float t0 = m0.x - d, t1 = m0.y - d, t2 = m0.z - d, t3 = m0.w - d;
                float t4 = m1.x - d, t5 = m1.y - d, t6 = m1.z - d, t7 = m1.w - d;
                a[mt] = (bf16x8){ (__bf16)__expf(-10.f * t0 * t0), (__bf16)__expf(-10.f * t1 * t1),
                                  (__bf16)__expf(-10.f * t2 * t2), (__bf16)__expf(-10.f * t3 * t3),
                                  (__bf16)__expf(-10.f * t4 * t4), (__bf16)__expf(-10.f * t5 * t5),
                                  (__bf16)__expf(-10.f * t6 * t6), (__bf16)__expf(-10.f * t7 * t7) };
            }
#pragma unroll
            for (int nt = 0; nt < 8; ++nt) {
                bf16x8 b = *(const bf16x8*)&B1s[(((kk * 4 + q) * 128) + nt * 16 + ln) * 8];
                acc1[0][nt] = __builtin_amdgcn_mfma_f32_16x16x32_bf16(a[0], b, acc1[0][nt], 0, 0, 0);
                acc1[1][nt] = __builtin_amdgcn_mfma_f32_16x16x32_bf16(a[1], b, acc1[1][nt], 0, 0, 0);
            }
        }
        // kk = 7: only q==0 lanes carry real values (RBF cols 96..99).
        {
            float4 m7 = *(const float4*)(mu + 96);
            const __bf16 zz = (__bf16)0.0f;
            const bool qz = (q == 0);
            bf16x8 a[2];
#pragma unroll
            for (int mt = 0; mt < 2; ++mt) {
                float d = dvA[mt];
                float t0 = m7.x - d, t1 = m7.y - d, t2 = m7.z - d, t3 = m7.w - d;
                a[mt] = (bf16x8){ qz ? (__bf16)__expf(-10.f * t0 * t0) : zz,
                                  qz ? (__bf16)__expf(-10.f * t1 * t1) : zz,
                                  qz ? (__bf16)__expf(-10.f * t2 * t2) : zz,
                                  qz ? (__bf16)__expf(-10.f * t3 * t3) : zz,
                                  zz, zz, zz, zz };
            }
#pragma unroll
            for (int nt = 0; nt < 8; ++nt) {
                bf16x8 b = *(const bf16x8*)&B1s[(((7 * 4 + q) * 128) + nt * 16 + ln) * 8];
                acc1[0][nt] = __builtin_amdgcn_mfma_f32_16x16x32_bf16(a[0], b, acc1[0][nt], 0, 0, 0);
                acc1[1][nt] = __builtin_amdgcn_mfma_f32_16x16x32_bf16(a[1], b, acc1[1][nt], 0, 0, 0);
            }
        }
        // kk = 0..3: gathered node features (issued at iteration start)
#pragma unroll
        for (int kk = 0; kk < 4; ++kk) {
#pragma unroll
            for (int nt = 0; nt < 8; ++nt) {
                bf16x8 b = *(const bf16x8*)&B1s[(((kk * 4 + q) * 128) + nt * 16 + ln) * 8];
                acc1[0][nt] = __builtin_amdgcn_mfma_f32_16x16x32_bf16(ag[kk][0], b, acc1[0][nt], 0, 0, 0);
                acc1[1][nt] = __builtin_amdgcn_mfma_f32_16x16x32_bf16(ag[kk][1], b, acc1[1][nt], 0, 0, 0);
            }
        }

        // ---- SiLU + wave-private transpose (C-layout -> row-major bf16) ----
#pragma unroll
        for (int mt = 0; mt < 2; ++mt)
#pragma unroll
            for (int nt = 0; nt < 8; ++nt)
#pragma unroll
                for (int r = 0; r < 4; ++r) {
                    float z = acc1[mt][nt][r];
                    float s = z * __builtin_amdgcn_rcpf(1.0f + __expf(-z));
                    Hw[(mt * 16 + q * 4 + r) * LDH2 + nt * 16 + ln] = (__bf16)s;
                }
        // Same-wave LDS RAW/WAR: DS pipe is in-order per wave; compiler sees
        // aliasing through Hs and keeps program order.

        // ---- Layer 2: [32 x 128] @ [128 x 64] ----
        fx4 acc2[2][4];
#pragma unroll
        for (int mt = 0; mt < 2; ++mt)
#pragma unroll
            for (int nt = 0; nt < 4; ++nt)
                acc2[mt][nt] = (fx4){0.f, 0.f, 0.f, 0.f};

#pragma unroll
        for (int kk = 0; kk < 4; ++kk) {
            bf16x8 a2[2];
#pragma unroll
            for (int mt = 0; mt < 2; ++mt)
                a2[mt] = *(const bf16x8*)&Hw[(mt * 16 + ln) * LDH2 + kk * 32 + q * 8];
#pragma unroll
            for (int nt = 0; nt < 4; ++nt) {
                bf16x8 b2 = *(const bf16x8*)&B2s[(((kk * 4 + q) * 64) + nt * 16 + ln) * 8];
                acc2[0][nt] = __builtin_amdgcn_mfma_f32_16x16x32_bf16(a2[0], b2, acc2[0][nt], 0, 0, 0);
                acc2[1][nt] = __builtin_amdgcn_mfma_f32_16x16x32_bf16(a2[1], b2, acc2[1][nt], 0, 0, 0);
            }
        }

        // ---- Store current chunk ----
        const int g0 = c * WEDGES;
#pragma unroll
        for (int mt = 0; mt < 2; ++mt)
#pragma unroll
            for (int nt = 0; nt < 4; ++nt)
#pragma unroll
                for (int r = 0; r < 4; ++r)
                    out[(size_t)(g0 + mt * 16 + q * 4 + r) * ODIM + nt * 16 + ln] = acc2[mt][nt][r];

        // ---- Rotate loop-carried indices ----
        if (haveN) {
#pragma unroll
            for (int mt = 0; mt < 2; ++mt) {
                nsA[mt] = nsB[mt];
                ndA[mt] = ndB[mt];
                dvA[mt] = dvB[mt];
            }
        }
        c = cn;
    }
}

extern "C" void kernel_launch(void* const* d_in, const int* in_sizes, int n_in,
                              void* d_out, int out_size, void* d_ws, size_t ws_size,
                              hipStream_t stream) {
    const float* h   = (const float*)d_in[0];
    const int*   src = (const int*)d_in[1];
    const int*   dst = (const int*)d_in[2];
    const float* en  = (const float*)d_in[3];
    const float* mu  = (const float*)d_in[4];
    const float* W1  = (const float*)d_in[5];
    const float* W2  = (const float*)d_in[6];

    __bf16* B1 = (__bf16*)d_ws;                          // 32768 bf16 = 64 KB
    __bf16* B2 = (__bf16*)((char*)d_ws + 65536);         // 8192 bf16  = 16 KB
    __bf16* HB = (__bf16*)((char*)d_ws + 81920);         // 3.2M bf16  = 6.4 MB

    const size_t ws_needed = 81920 + (size_t)HN8 * 8 * sizeof(__bf16);
    const bool   use_hb    = ws_size >= ws_needed;

    pack_w<<<160, 256, 0, stream>>>(W1, W2, B1, B2);

    const int E = in_sizes[1];                 // 800000
    const int nchunk = E / WEDGES;             // 25000

    if (use_hb) {
        pack_h<<<(HN8 + 255) / 256, 256, 0, stream>>>(h, HB);
        edges_fused<true><<<GRID, 512, 0, stream>>>(h, HB, src, dst, en, mu, B1, B2, (float*)d_out, nchunk);
    } else {
        edges_fused<false><<<GRID, 512, 0, stream>>>(h, nullptr, src, dst, en, mu, B1, B2, (float*)d_out, nchunk);
    }
}

// Round 5
// 324.377 us; speedup vs baseline: 1.3761x; 1.3488x over previous
//
#include <hip/hip_runtime.h>
#include <hip/hip_bf16.h>

// Edges GNN message MLP: per-edge RBF(100) + gather h[src],h[dst] (64+64)
// -> Linear(228->128) -> SiLU -> Linear(128->64).
// R8 design: R5 structure (non-persistent, no loop -- both persistent
// variants R6/R7 spilled: 128 VGPR + ~600MB scratch fetch), but 16-wave
// (1024-thread) blocks to double occupancy. Enabled by halving the per-wave
// transpose tile: layer 2 consumes H one 16-row m-tile at a time, so the
// epilogue is split per mt (SiLU+transpose 16 rows -> layer2 -> store, tile
// reused for mt=1; same-wave DS pipe is in-order so reuse is race-free).
// LDS: 64K (B1) + 16K (B2) + 16 waves x 4.25K (Hs) = 148 KB -> 1 block/CU,
// 16 waves/CU = 4 waves/SIMD (was 2).

#define FEAT     64
#define NMU      100
#define K1_REAL  228
#define HID      128
#define ODIM     64
#define K2       128
#define WEDGES   32        // edges per wave
#define NWAVES   16
#define BEDGES   (WEDGES * NWAVES)   // 512 edges per block
#define LDH2     136       // bf16 leading dim of per-wave H tile (16B-aligned rows)
#define HROWS    16        // per-wave transpose tile rows (one m-tile)
#define HN8      400000    // (50000*64)/8 bf16x8 groups in h

typedef __bf16 bf16x8 __attribute__((ext_vector_type(8)));
typedef float  fx4    __attribute__((ext_vector_type(4)));

// Pack W1 [128 x 228] and W2 [64 x 128] fp32 -> bf16 MFMA B-fragment order.
// B1[((kk*4+q)*128 + n)*8 + j] = W1[n][kk*32 + q*8 + j]  (0 if k >= 228)
// B2[((kk*4+q)*64  + n)*8 + j] = W2[n][kk*32 + q*8 + j]
__global__ void pack_w(const float* __restrict__ W1, const float* __restrict__ W2,
                       __bf16* __restrict__ B1, __bf16* __restrict__ B2) {
    int i = blockIdx.x * 256 + threadIdx.x;     // 0..40959
    if (i < 32768) {
        int j  = i & 7;
        int n  = (i >> 3) & 127;
        int qk = i >> 10;
        int k  = (qk >> 2) * 32 + (qk & 3) * 8 + j;
        float v = (k < K1_REAL) ? W1[n * K1_REAL + k] : 0.0f;
        B1[i] = (__bf16)v;
    } else {
        int t = i - 32768;
        int j  = t & 7;
        int n  = (t >> 3) & 63;
        int qk = t >> 9;
        int k  = (qk >> 2) * 32 + (qk & 3) * 8 + j;
        B2[t] = (__bf16)W2[n * K2 + k];
    }
}

// Convert h [50000 x 64] fp32 -> bf16 table (row-major, same layout).
__global__ void pack_h(const float* __restrict__ h, __bf16* __restrict__ hb) {
    int i = blockIdx.x * 256 + threadIdx.x;     // one bf16x8 group each
    if (i >= HN8) return;
    const float4* p = (const float4*)h + (size_t)i * 2;
    float4 v0 = p[0];
    float4 v1 = p[1];
    bf16x8 b = { (__bf16)v0.x, (__bf16)v0.y, (__bf16)v0.z, (__bf16)v0.w,
                 (__bf16)v1.x, (__bf16)v1.y, (__bf16)v1.z, (__bf16)v1.w };
    ((bf16x8*)hb)[i] = b;
}

__device__ __forceinline__ bf16x8 hfrag_f32(const float* __restrict__ h, int node, int cb) {
    const float4* p = (const float4*)(h + (size_t)node * FEAT + cb);
    float4 v0 = p[0];
    float4 v1 = p[1];
    bf16x8 a = { (__bf16)v0.x, (__bf16)v0.y, (__bf16)v0.z, (__bf16)v0.w,
                 (__bf16)v1.x, (__bf16)v1.y, (__bf16)v1.z, (__bf16)v1.w };
    return a;
}

template<bool HB16>
__global__ __launch_bounds__(1024, 4)
void edges_fused(const float* __restrict__ h,
                 const __bf16* __restrict__ hb,
                 const int*   __restrict__ src,
                 const int*   __restrict__ dst,
                 const float* __restrict__ enorm,
                 const float* __restrict__ mu,
                 const __bf16* __restrict__ B1,
                 const __bf16* __restrict__ B2,
                 float* __restrict__ out,
                 int E) {
    // 64K + 16K + 16*4.25K = 148 KB static LDS -> 1 block/CU.
    __shared__ __bf16 B1s[32768];
    __shared__ __bf16 B2s[8192];
    __shared__ __bf16 Hs[NWAVES * HROWS * LDH2];

    const int tid  = threadIdx.x;
    const int w    = tid >> 6;
    const int lane = tid & 63;
    const int ln   = lane & 15;
    const int q    = lane >> 4;
    const int g0   = blockIdx.x * BEDGES + w * WEDGES;
    const bool act = (g0 < E);          // wave-level tail guard (E % 32 == 0)

    // ---- Edge data + gathers into registers (before the staging barrier,
    // so gather latency overlaps the weight stage) ----
    int nsrc[2], ndst[2];
    float dval[2];
    bf16x8 ag[4][2];     // [kk][mt] gathered A-fragments
    if (act) {
#pragma unroll
        for (int mt = 0; mt < 2; ++mt) {
            int e = g0 + mt * 16 + ln;
            nsrc[mt] = src[e];
            ndst[mt] = dst[e];
            dval[mt] = enorm[e];
        }
#pragma unroll
        for (int kk = 0; kk < 4; ++kk) {
            const int cb = (kk & 1) * 32 + q * 8;
#pragma unroll
            for (int mt = 0; mt < 2; ++mt) {
                int node = (kk < 2) ? nsrc[mt] : ndst[mt];
                if constexpr (HB16)
                    ag[kk][mt] = *(const bf16x8*)(hb + (size_t)node * FEAT + cb);
                else
                    ag[kk][mt] = hfrag_f32(h, node, cb);
            }
        }
    }

    // ---- Stage weights into LDS (once per block; all threads) ----
    {
        const bf16x8* gB1 = (const bf16x8*)B1;
        const bf16x8* gB2 = (const bf16x8*)B2;
        bf16x8* sB1 = (bf16x8*)B1s;
        bf16x8* sB2 = (bf16x8*)B2s;
#pragma unroll
        for (int it = 0; it < 4; ++it) {   // 4096 groups / 1024 threads
            int g = it * 1024 + tid;
            sB1[g] = gB1[g];
        }
        sB2[tid] = gB2[tid];               // 1024 groups / 1024 threads
    }
    __syncthreads();
    if (!act) return;                      // after the only barrier

    // ---- Layer 1: [32 x 256pad] @ [256 x 128] ----
    fx4 acc1[2][8];
#pragma unroll
    for (int mt = 0; mt < 2; ++mt)
#pragma unroll
        for (int nt = 0; nt < 8; ++nt)
            acc1[mt][nt] = (fx4){0.f, 0.f, 0.f, 0.f};

    // kk = 4..6 first (RBF, pure VALU+MFMA) -- gives the in-flight gathers
    // maximum slack before kk=0 consumes ag.
#pragma unroll
    for (int kk = 4; kk < 7; ++kk) {
        const int c0 = (kk - 4) * 32 + q * 8;
        float4 m0 = *(const float4*)(mu + c0);
        float4 m1 = *(const float4*)(mu + c0 + 4);
        bf16x8 a[2];
#pragma unroll
        for (int mt = 0; mt < 2; ++mt) {
            float d = dval[mt];
            float t0 = m0.x - d, t1 = m0.y - d, t2 = m0.z - d, t3 = m0.w - d;
            float t4 = m1.x - d, t5 = m1.y - d, t6 = m1.z - d, t7 = m1.w - d;
            a[mt] = (bf16x8){ (__bf16)__expf(-10.f * t0 * t0), (__bf16)__expf(-10.f * t1 * t1),
                              (__bf16)__expf(-10.f * t2 * t2), (__bf16)__expf(-10.f * t3 * t3),
                              (__bf16)__expf(-10.f * t4 * t4), (__bf16)__expf(-10.f * t5 * t5),
                              (__bf16)__expf(-10.f * t6 * t6), (__bf16)__expf(-10.f * t7 * t7) };
        }
#pragma unroll
        for (int nt = 0; nt < 8; ++nt) {
            bf16x8 b = *(const bf16x8*)&B1s[(((kk * 4 + q) * 128) + nt * 16 + ln) * 8];
            acc1[0][nt] = __builtin_amdgcn_mfma_f32_16x16x32_bf16(a[0], b, acc1[0][nt], 0, 0, 0);
            acc1[1][nt] = __builtin_amdgcn_mfma_f32_16x16x32_bf16(a[1], b, acc1[1][nt], 0, 0, 0);
        }
    }
    // kk = 7: only q==0 lanes carry real values (RBF cols 96..99).
    {
        float4 m7 = *(const float4*)(mu + 96);
        const __bf16 zz = (__bf16)0.0f;
        const bool qz = (q == 0);
        bf16x8 a[2];
#pragma unroll
        for (int mt = 0; mt < 2; ++mt) {
            float d = dval[mt];
            float t0 = m7.x - d, t1 = m7.y - d, t2 = m7.z - d, t3 = m7.w - d;
            a[mt] = (bf16x8){ qz ? (__bf16)__expf(-10.f * t0 * t0) : zz,
                              qz ? (__bf16)__expf(-10.f * t1 * t1) : zz,
                              qz ? (__bf16)__expf(-10.f * t2 * t2) : zz,
                              qz ? (__bf16)__expf(-10.f * t3 * t3) : zz,
                              zz, zz, zz, zz };
        }
#pragma unroll
        for (int nt = 0; nt < 8; ++nt) {
            bf16x8 b = *(const bf16x8*)&B1s[(((7 * 4 + q) * 128) + nt * 16 + ln) * 8];
            acc1[0][nt] = __builtin_amdgcn_mfma_f32_16x16x32_bf16(a[0], b, acc1[0][nt], 0, 0, 0);
            acc1[1][nt] = __builtin_amdgcn_mfma_f32_16x16x32_bf16(a[1], b, acc1[1][nt], 0, 0, 0);
        }
    }
    // kk = 0..3: gathered node features (issued before staging)
#pragma unroll
    for (int kk = 0; kk < 4; ++kk) {
#pragma unroll
        for (int nt = 0; nt < 8; ++nt) {
            bf16x8 b = *(const bf16x8*)&B1s[(((kk * 4 + q) * 128) + nt * 16 + ln) * 8];
            acc1[0][nt] = __builtin_amdgcn_mfma_f32_16x16x32_bf16(ag[kk][0], b, acc1[0][nt], 0, 0, 0);
            acc1[1][nt] = __builtin_amdgcn_mfma_f32_16x16x32_bf16(ag[kk][1], b, acc1[1][nt], 0, 0, 0);
        }
    }

    // ---- Epilogue, per m-tile: SiLU+transpose 16 rows -> layer2 -> store.
    // The 16-row tile is reused across mt; same-wave DS ops are in-order, so
    // mt=1 writes cannot pass mt=0 reads.
    __bf16* Hw = &Hs[w * HROWS * LDH2];
#pragma unroll
    for (int mt = 0; mt < 2; ++mt) {
        // SiLU + wave-private transpose (C-layout -> row-major bf16)
#pragma unroll
        for (int nt = 0; nt < 8; ++nt)
#pragma unroll
            for (int r = 0; r < 4; ++r) {
                float z = acc1[mt][nt][r];
                float s = z * __builtin_amdgcn_rcpf(1.0f + __expf(-z));
                Hw[(q * 4 + r) * LDH2 + nt * 16 + ln] = (__bf16)s;
            }

        // Layer 2: [16 x 128] @ [128 x 64]
        fx4 acc2[4];
#pragma unroll
        for (int nt = 0; nt < 4; ++nt)
            acc2[nt] = (fx4){0.f, 0.f, 0.f, 0.f};
#pragma unroll
        for (int kk = 0; kk < 4; ++kk) {
            bf16x8 a2 = *(const bf16x8*)&Hw[ln * LDH2 + kk * 32 + q * 8];
#pragma unroll
            for (int nt = 0; nt < 4; ++nt) {
                bf16x8 b2 = *(const bf16x8*)&B2s[(((kk * 4 + q) * 64) + nt * 16 + ln) * 8];
                acc2[nt] = __builtin_amdgcn_mfma_f32_16x16x32_bf16(a2, b2, acc2[nt], 0, 0, 0);
            }
        }

        // Store this m-tile
#pragma unroll
        for (int nt = 0; nt < 4; ++nt)
#pragma unroll
            for (int r = 0; r < 4; ++r)
                out[(size_t)(g0 + mt * 16 + q * 4 + r) * ODIM + nt * 16 + ln] = acc2[nt][r];
    }
}

extern "C" void kernel_launch(void* const* d_in, const int* in_sizes, int n_in,
                              void* d_out, int out_size, void* d_ws, size_t ws_size,
                              hipStream_t stream) {
    const float* h   = (const float*)d_in[0];
    const int*   src = (const int*)d_in[1];
    const int*   dst = (const int*)d_in[2];
    const float* en  = (const float*)d_in[3];
    const float* mu  = (const float*)d_in[4];
    const float* W1  = (const float*)d_in[5];
    const float* W2  = (const float*)d_in[6];

    __bf16* B1 = (__bf16*)d_ws;                          // 32768 bf16 = 64 KB
    __bf16* B2 = (__bf16*)((char*)d_ws + 65536);         // 8192 bf16  = 16 KB
    __bf16* HB = (__bf16*)((char*)d_ws + 81920);         // 3.2M bf16  = 6.4 MB

    const size_t ws_needed = 81920 + (size_t)HN8 * 8 * sizeof(__bf16);
    const bool   use_hb    = ws_size >= ws_needed;

    pack_w<<<160, 256, 0, stream>>>(W1, W2, B1, B2);

    const int E = in_sizes[1];                 // 800000
    const int nblocks = (E + BEDGES - 1) / BEDGES;   // 1563

    if (use_hb) {
        pack_h<<<(HN8 + 255) / 256, 256, 0, stream>>>(h, HB);
        edges_fused<true><<<nblocks, 1024, 0, stream>>>(h, HB, src, dst, en, mu, B1, B2, (float*)d_out, E);
    } else {
        edges_fused<false><<<nblocks, 1024, 0, stream>>>(h, nullptr, src, dst, en, mu, B1, B2, (float*)d_out, E);
    }
}

// Round 6
// 304.953 us; speedup vs baseline: 1.4638x; 1.0637x over previous
//
#include <hip/hip_runtime.h>
#include <hip/hip_bf16.h>

// Edges GNN message MLP: per-edge RBF(100) + gather h[src],h[dst] (64+64)
// -> Linear(228->128) -> SiLU -> Linear(128->64).
// R9 design: R8 (16-wave blocks, 4 waves/SIMD, per-mt epilogue) MINUS the
// register spill. A 1024-thr block structurally caps regs at 128/lane
// (16 waves must co-reside); R8's ag[4][2] (32 VGPR) pushed past it
// (WRITE_SIZE 290MB vs 200MB output = scratch). R9 staggers the gathers:
// ag[2][2] (16 VGPR) -- src-half issued before the weight stage (covered by
// stage+barrier+RBF), consumed at kk=0,1; dst-half issued into the SAME regs,
// consumed at kk=2,3 (covered by kk=0,1's 32 MFMAs + 4-wave TLP).
// LDS: 64K (B1) + 16K (B2) + 16 x 4.25K (Hs) = 148 KB -> 1 block/CU.

#define FEAT     64
#define NMU      100
#define K1_REAL  228
#define HID      128
#define ODIM     64
#define K2       128
#define WEDGES   32        // edges per wave
#define NWAVES   16
#define BEDGES   (WEDGES * NWAVES)   // 512 edges per block
#define LDH2     136       // bf16 leading dim of per-wave H tile (16B-aligned rows)
#define HROWS    16        // per-wave transpose tile rows (one m-tile)
#define HN8      400000    // (50000*64)/8 bf16x8 groups in h

typedef __bf16 bf16x8 __attribute__((ext_vector_type(8)));
typedef float  fx4    __attribute__((ext_vector_type(4)));

// Pack W1 [128 x 228] and W2 [64 x 128] fp32 -> bf16 MFMA B-fragment order.
// B1[((kk*4+q)*128 + n)*8 + j] = W1[n][kk*32 + q*8 + j]  (0 if k >= 228)
// B2[((kk*4+q)*64  + n)*8 + j] = W2[n][kk*32 + q*8 + j]
__global__ void pack_w(const float* __restrict__ W1, const float* __restrict__ W2,
                       __bf16* __restrict__ B1, __bf16* __restrict__ B2) {
    int i = blockIdx.x * 256 + threadIdx.x;     // 0..40959
    if (i < 32768) {
        int j  = i & 7;
        int n  = (i >> 3) & 127;
        int qk = i >> 10;
        int k  = (qk >> 2) * 32 + (qk & 3) * 8 + j;
        float v = (k < K1_REAL) ? W1[n * K1_REAL + k] : 0.0f;
        B1[i] = (__bf16)v;
    } else {
        int t = i - 32768;
        int j  = t & 7;
        int n  = (t >> 3) & 63;
        int qk = t >> 9;
        int k  = (qk >> 2) * 32 + (qk & 3) * 8 + j;
        B2[t] = (__bf16)W2[n * K2 + k];
    }
}

// Convert h [50000 x 64] fp32 -> bf16 table (row-major, same layout).
__global__ void pack_h(const float* __restrict__ h, __bf16* __restrict__ hb) {
    int i = blockIdx.x * 256 + threadIdx.x;     // one bf16x8 group each
    if (i >= HN8) return;
    const float4* p = (const float4*)h + (size_t)i * 2;
    float4 v0 = p[0];
    float4 v1 = p[1];
    bf16x8 b = { (__bf16)v0.x, (__bf16)v0.y, (__bf16)v0.z, (__bf16)v0.w,
                 (__bf16)v1.x, (__bf16)v1.y, (__bf16)v1.z, (__bf16)v1.w };
    ((bf16x8*)hb)[i] = b;
}

__device__ __forceinline__ bf16x8 hfrag_f32(const float* __restrict__ h, int node, int cb) {
    const float4* p = (const float4*)(h + (size_t)node * FEAT + cb);
    float4 v0 = p[0];
    float4 v1 = p[1];
    bf16x8 a = { (__bf16)v0.x, (__bf16)v0.y, (__bf16)v0.z, (__bf16)v0.w,
                 (__bf16)v1.x, (__bf16)v1.y, (__bf16)v1.z, (__bf16)v1.w };
    return a;
}

template<bool HB16>
__global__ __launch_bounds__(1024, 4)
void edges_fused(const float* __restrict__ h,
                 const __bf16* __restrict__ hb,
                 const int*   __restrict__ src,
                 const int*   __restrict__ dst,
                 const float* __restrict__ enorm,
                 const float* __restrict__ mu,
                 const __bf16* __restrict__ B1,
                 const __bf16* __restrict__ B2,
                 float* __restrict__ out,
                 int E) {
    // 64K + 16K + 16*4.25K = 148 KB static LDS -> 1 block/CU.
    __shared__ __bf16 B1s[32768];
    __shared__ __bf16 B2s[8192];
    __shared__ __bf16 Hs[NWAVES * HROWS * LDH2];

    const int tid  = threadIdx.x;
    const int w    = tid >> 6;
    const int lane = tid & 63;
    const int ln   = lane & 15;
    const int q    = lane >> 4;
    const int g0   = blockIdx.x * BEDGES + w * WEDGES;
    const bool act = (g0 < E);          // wave-level tail guard (E % 32 == 0)

    // ---- Edge data + SRC gathers into registers (before the staging
    // barrier, so gather latency overlaps the weight stage) ----
    int ndst[2];
    float dval[2];
    bf16x8 ag[2][2];     // [half][mt] gathered A-fragments (16 VGPRs live)
    if (act) {
        int nsrc[2];
#pragma unroll
        for (int mt = 0; mt < 2; ++mt) {
            int e = g0 + mt * 16 + ln;
            nsrc[mt] = src[e];
            ndst[mt] = dst[e];
            dval[mt] = enorm[e];
        }
        // src half: kk=0 (cols 0..31), kk=1 (cols 32..63)
#pragma unroll
        for (int kk = 0; kk < 2; ++kk) {
            const int cb = kk * 32 + q * 8;
#pragma unroll
            for (int mt = 0; mt < 2; ++mt) {
                if constexpr (HB16)
                    ag[kk][mt] = *(const bf16x8*)(hb + (size_t)nsrc[mt] * FEAT + cb);
                else
                    ag[kk][mt] = hfrag_f32(h, nsrc[mt], cb);
            }
        }
    }

    // ---- Stage weights into LDS (once per block; all threads) ----
    {
        const bf16x8* gB1 = (const bf16x8*)B1;
        const bf16x8* gB2 = (const bf16x8*)B2;
        bf16x8* sB1 = (bf16x8*)B1s;
        bf16x8* sB2 = (bf16x8*)B2s;
#pragma unroll
        for (int it = 0; it < 4; ++it) {   // 4096 groups / 1024 threads
            int g = it * 1024 + tid;
            sB1[g] = gB1[g];
        }
        sB2[tid] = gB2[tid];               // 1024 groups / 1024 threads
    }
    __syncthreads();
    if (!act) return;                      // after the only barrier

    // ---- Layer 1: [32 x 256pad] @ [256 x 128] ----
    fx4 acc1[2][8];
#pragma unroll
    for (int mt = 0; mt < 2; ++mt)
#pragma unroll
        for (int nt = 0; nt < 8; ++nt)
            acc1[mt][nt] = (fx4){0.f, 0.f, 0.f, 0.f};

    // kk = 4..6 first (RBF, pure VALU+MFMA) -- extra slack for src gathers.
#pragma unroll
    for (int kk = 4; kk < 7; ++kk) {
        const int c0 = (kk - 4) * 32 + q * 8;
        float4 m0 = *(const float4*)(mu + c0);
        float4 m1 = *(const float4*)(mu + c0 + 4);
        bf16x8 a[2];
#pragma unroll
        for (int mt = 0; mt < 2; ++mt) {
            float d = dval[mt];
            float t0 = m0.x - d, t1 = m0.y - d, t2 = m0.z - d, t3 = m0.w - d;
            float t4 = m1.x - d, t5 = m1.y - d, t6 = m1.z - d, t7 = m1.w - d;
            a[mt] = (bf16x8){ (__bf16)__expf(-10.f * t0 * t0), (__bf16)__expf(-10.f * t1 * t1),
                              (__bf16)__expf(-10.f * t2 * t2), (__bf16)__expf(-10.f * t3 * t3),
                              (__bf16)__expf(-10.f * t4 * t4), (__bf16)__expf(-10.f * t5 * t5),
                              (__bf16)__expf(-10.f * t6 * t6), (__bf16)__expf(-10.f * t7 * t7) };
        }
#pragma unroll
        for (int nt = 0; nt < 8; ++nt) {
            bf16x8 b = *(const bf16x8*)&B1s[(((kk * 4 + q) * 128) + nt * 16 + ln) * 8];
            acc1[0][nt] = __builtin_amdgcn_mfma_f32_16x16x32_bf16(a[0], b, acc1[0][nt], 0, 0, 0);
            acc1[1][nt] = __builtin_amdgcn_mfma_f32_16x16x32_bf16(a[1], b, acc1[1][nt], 0, 0, 0);
        }
    }
    // kk = 7: only q==0 lanes carry real values (RBF cols 96..99).
    {
        float4 m7 = *(const float4*)(mu + 96);
        const __bf16 zz = (__bf16)0.0f;
        const bool qz = (q == 0);
        bf16x8 a[2];
#pragma unroll
        for (int mt = 0; mt < 2; ++mt) {
            float d = dval[mt];
            float t0 = m7.x - d, t1 = m7.y - d, t2 = m7.z - d, t3 = m7.w - d;
            a[mt] = (bf16x8){ qz ? (__bf16)__expf(-10.f * t0 * t0) : zz,
                              qz ? (__bf16)__expf(-10.f * t1 * t1) : zz,
                              qz ? (__bf16)__expf(-10.f * t2 * t2) : zz,
                              qz ? (__bf16)__expf(-10.f * t3 * t3) : zz,
                              zz, zz, zz, zz };
        }
#pragma unroll
        for (int nt = 0; nt < 8; ++nt) {
            bf16x8 b = *(const bf16x8*)&B1s[(((7 * 4 + q) * 128) + nt * 16 + ln) * 8];
            acc1[0][nt] = __builtin_amdgcn_mfma_f32_16x16x32_bf16(a[0], b, acc1[0][nt], 0, 0, 0);
            acc1[1][nt] = __builtin_amdgcn_mfma_f32_16x16x32_bf16(a[1], b, acc1[1][nt], 0, 0, 0);
        }
    }
    // kk = 0..1: src features (in registers since before staging)
#pragma unroll
    for (int kk = 0; kk < 2; ++kk) {
#pragma unroll
        for (int nt = 0; nt < 8; ++nt) {
            bf16x8 b = *(const bf16x8*)&B1s[(((kk * 4 + q) * 128) + nt * 16 + ln) * 8];
            acc1[0][nt] = __builtin_amdgcn_mfma_f32_16x16x32_bf16(ag[kk][0], b, acc1[0][nt], 0, 0, 0);
            acc1[1][nt] = __builtin_amdgcn_mfma_f32_16x16x32_bf16(ag[kk][1], b, acc1[1][nt], 0, 0, 0);
        }
    }
    // dst gathers into the SAME registers (ag dead after kk=1 consume)
#pragma unroll
    for (int kk = 0; kk < 2; ++kk) {
        const int cb = kk * 32 + q * 8;
#pragma unroll
        for (int mt = 0; mt < 2; ++mt) {
            if constexpr (HB16)
                ag[kk][mt] = *(const bf16x8*)(hb + (size_t)ndst[mt] * FEAT + cb);
            else
                ag[kk][mt] = hfrag_f32(h, ndst[mt], cb);
        }
    }
    // kk = 2..3: dst features
#pragma unroll
    for (int kk = 2; kk < 4; ++kk) {
#pragma unroll
        for (int nt = 0; nt < 8; ++nt) {
            bf16x8 b = *(const bf16x8*)&B1s[(((kk * 4 + q) * 128) + nt * 16 + ln) * 8];
            acc1[0][nt] = __builtin_amdgcn_mfma_f32_16x16x32_bf16(ag[kk - 2][0], b, acc1[0][nt], 0, 0, 0);
            acc1[1][nt] = __builtin_amdgcn_mfma_f32_16x16x32_bf16(ag[kk - 2][1], b, acc1[1][nt], 0, 0, 0);
        }
    }

    // ---- Epilogue, per m-tile: SiLU+transpose 16 rows -> layer2 -> store.
    // The 16-row tile is reused across mt; same-wave DS ops are in-order.
    __bf16* Hw = &Hs[w * HROWS * LDH2];
#pragma unroll
    for (int mt = 0; mt < 2; ++mt) {
        // SiLU + wave-private transpose (C-layout -> row-major bf16)
#pragma unroll
        for (int nt = 0; nt < 8; ++nt)
#pragma unroll
            for (int r = 0; r < 4; ++r) {
                float z = acc1[mt][nt][r];
                float s = z * __builtin_amdgcn_rcpf(1.0f + __expf(-z));
                Hw[(q * 4 + r) * LDH2 + nt * 16 + ln] = (__bf16)s;
            }

        // Layer 2: [16 x 128] @ [128 x 64]
        fx4 acc2[4];
#pragma unroll
        for (int nt = 0; nt < 4; ++nt)
            acc2[nt] = (fx4){0.f, 0.f, 0.f, 0.f};
#pragma unroll
        for (int kk = 0; kk < 4; ++kk) {
            bf16x8 a2 = *(const bf16x8*)&Hw[ln * LDH2 + kk * 32 + q * 8];
#pragma unroll
            for (int nt = 0; nt < 4; ++nt) {
                bf16x8 b2 = *(const bf16x8*)&B2s[(((kk * 4 + q) * 64) + nt * 16 + ln) * 8];
                acc2[nt] = __builtin_amdgcn_mfma_f32_16x16x32_bf16(a2, b2, acc2[nt], 0, 0, 0);
            }
        }

        // Store this m-tile
#pragma unroll
        for (int nt = 0; nt < 4; ++nt)
#pragma unroll
            for (int r = 0; r < 4; ++r)
                out[(size_t)(g0 + mt * 16 + q * 4 + r) * ODIM + nt * 16 + ln] = acc2[nt][r];
    }
}

extern "C" void kernel_launch(void* const* d_in, const int* in_sizes, int n_in,
                              void* d_out, int out_size, void* d_ws, size_t ws_size,
                              hipStream_t stream) {
    const float* h   = (const float*)d_in[0];
    const int*   src = (const int*)d_in[1];
    const int*   dst = (const int*)d_in[2];
    const float* en  = (const float*)d_in[3];
    const float* mu  = (const float*)d_in[4];
    const float* W1  = (const float*)d_in[5];
    const float* W2  = (const float*)d_in[6];

    __bf16* B1 = (__bf16*)d_ws;                          // 32768 bf16 = 64 KB
    __bf16* B2 = (__bf16*)((char*)d_ws + 65536);         // 8192 bf16  = 16 KB
    __bf16* HB = (__bf16*)((char*)d_ws + 81920);         // 3.2M bf16  = 6.4 MB

    const size_t ws_needed = 81920 + (size_t)HN8 * 8 * sizeof(__bf16);
    const bool   use_hb    = ws_size >= ws_needed;

    pack_w<<<160, 256, 0, stream>>>(W1, W2, B1, B2);

    const int E = in_sizes[1];                 // 800000
    const int nblocks = (E + BEDGES - 1) / BEDGES;   // 1563

    if (use_hb) {
        pack_h<<<(HN8 + 255) / 256, 256, 0, stream>>>(h, HB);
        edges_fused<true><<<nblocks, 1024, 0, stream>>>(h, HB, src, dst, en, mu, B1, B2, (float*)d_out, E);
    } else {
        edges_fused<false><<<nblocks, 1024, 0, stream>>>(h, nullptr, src, dst, en, mu, B1, B2, (float*)d_out, E);
    }
}

// Round 9
// 303.919 us; speedup vs baseline: 1.4687x; 1.0034x over previous
//
#include <hip/hip_runtime.h>
#include <hip/hip_bf16.h>

// Edges GNN message MLP: per-edge RBF(100) + gather h[src],h[dst] (64+64)
// -> Linear(228->128) -> SiLU -> Linear(128->64).
// R11 design: operand-swapped 32x32x16 MFMA, ZERO-shuffle layer1->layer2
// hand-off, no Hs LDS tile.
// Layer1 computes H^T = W1 . X^T (A = W1 tiles from LDS, B = per-edge X^T
// fragments from gathers/RBF). C-layout: col = lane&31 = edge, so each lane
// holds its own edge's H values. Layer2's B-fragment k-slot -> H-row mapping
// is OUR choice (it only has to match the W2 pack order), so we pick the
// permutation rho(s, 8*h5+j) = 32*(s>>1) + 16*(s&1) + 8*(j>>2) + 4*h5 + (j&3)
// which makes every k-slot land on data the lane ALREADY holds: the
// transpose is absorbed into pack_w's W2 column permutation. (R10 used
// permlane32_swap here; that builtin is the prime suspect in two container
// failures and is now gone entirely.)
// MFMA count drops 160->76 vs the 16x16 design (pad k-step skipped).
// LDS = 60K (B1) + 16K (B2) = 76 KB -> 2 blocks/CU @ 512 thr, one barrier,
// barrier-free epilogue, dwordx4 stores.

#define FEAT      64
#define NMU       100
#define K1_REAL   228
#define WEDGES    32        // edges per wave (one 32-row m-tile)
#define NWAVES    8
#define BEDGES    (WEDGES * NWAVES)   // 256 edges per block
#define HN8       400000    // (50000*64)/8 bf16x8 groups in h
#define B1N_ELEMS 30720     // 30 (ksh) * 128 (n) * 8 (j) bf16 = 60 KB
#define B2N_ELEMS 8192      // 16 (sh) * 64 (n2) * 8 (j) bf16 = 16 KB

typedef __bf16  bf16x8 __attribute__((ext_vector_type(8)));
typedef float   fx16   __attribute__((ext_vector_type(16)));

// Pack W1 [128 x 228] -> B1[(ksh*128 + n)*8 + j] = W1[n][8*ksh + j]
// (ksh = ks*2 + h5, ks = 0..14; zero for k >= 228).
// This is the 32x32x16 A-fragment order: lane l reads row n = tile*32 +
// (l&31), k = 8*(l>>5) + j as one contiguous 16B group.
// Pack W2 [64 x 128] -> B2[(sh*64 + n2)*8 + j] = W2[n2][rho] with
// rho = 32*(sh>>2) + 16*((sh>>1)&1) + 8*(j>>2) + 4*(sh&1) + (j&3):
// the k-slot -> H-row permutation that makes layer2's B-fragment lane-local.
__global__ void pack_w(const float* __restrict__ W1, const float* __restrict__ W2,
                       __bf16* __restrict__ B1, __bf16* __restrict__ B2) {
    int i = blockIdx.x * 256 + threadIdx.x;     // 0..38911
    if (i < B1N_ELEMS) {
        int j   = i & 7;
        int n   = (i >> 3) & 127;
        int ksh = i >> 10;                      // 0..29
        int k   = ksh * 8 + j;                  // 0..239
        float v = (k < K1_REAL) ? W1[n * K1_REAL + k] : 0.0f;
        B1[i] = (__bf16)v;
    } else if (i < B1N_ELEMS + B2N_ELEMS) {
        int t   = i - B1N_ELEMS;
        int j   = t & 7;
        int n2  = (t >> 3) & 63;
        int sh  = t >> 9;                       // 0..15
        int rho = ((sh >> 2) << 5) | (((sh >> 1) & 1) << 4)
                | ((j >> 2) << 3) | ((sh & 1) << 2) | (j & 3);
        B2[t] = (__bf16)W2[n2 * 128 + rho];
    }
}

// Convert h [50000 x 64] fp32 -> bf16 table (row-major, same layout).
__global__ void pack_h(const float* __restrict__ h, __bf16* __restrict__ hb) {
    int i = blockIdx.x * 256 + threadIdx.x;     // one bf16x8 group each
    if (i >= HN8) return;
    const float4* p = (const float4*)h + (size_t)i * 2;
    float4 v0 = p[0];
    float4 v1 = p[1];
    bf16x8 b = { (__bf16)v0.x, (__bf16)v0.y, (__bf16)v0.z, (__bf16)v0.w,
                 (__bf16)v1.x, (__bf16)v1.y, (__bf16)v1.z, (__bf16)v1.w };
    ((bf16x8*)hb)[i] = b;
}

__device__ __forceinline__ bf16x8 hfrag_f32(const float* __restrict__ h, int node, int cb) {
    const float4* p = (const float4*)(h + (size_t)node * FEAT + cb);
    float4 v0 = p[0];
    float4 v1 = p[1];
    bf16x8 a = { (__bf16)v0.x, (__bf16)v0.y, (__bf16)v0.z, (__bf16)v0.w,
                 (__bf16)v1.x, (__bf16)v1.y, (__bf16)v1.z, (__bf16)v1.w };
    return a;
}

__device__ __forceinline__ float silu(float z) {
    // v_rcp_f32 (~1 ulp) -- error far below bf16 storage rounding.
    return z * __builtin_amdgcn_rcpf(1.0f + __expf(-z));
}

__device__ __forceinline__ uint32_t pkbf16(float x, float y) {
    union { __bf16 b; uint16_t u; } cx, cy;
    cx.b = (__bf16)x; cy.b = (__bf16)y;
    return (uint32_t)cx.u | ((uint32_t)cy.u << 16);
}

template<bool HB16>
__global__ __launch_bounds__(512, 4)
void edges_fused(const float* __restrict__ h,
                 const __bf16* __restrict__ hb,
                 const int*   __restrict__ src,
                 const int*   __restrict__ dst,
                 const float* __restrict__ enorm,
                 const float* __restrict__ mu,
                 const __bf16* __restrict__ B1,
                 const __bf16* __restrict__ B2,
                 float* __restrict__ out,
                 int E) {
    // 60K + 16K = 76 KB static LDS -> 2 blocks/CU.
    __shared__ __align__(16) __bf16 B1s[B1N_ELEMS];
    __shared__ __align__(16) __bf16 B2s[B2N_ELEMS];

    const int tid = threadIdx.x;
    const int w   = tid >> 6;
    const int m   = tid & 31;          // edge within the wave's 32-row tile
    const int h5  = (tid >> 5) & 1;    // lane>>5: k-half selector
    const int g0  = blockIdx.x * BEDGES + w * WEDGES;
    const bool act = (g0 < E);

    // ---- Edge data + SRC gathers (before the staging barrier) ----
    int ndst;
    float dval;
    bf16x8 ags[4];                     // 16 VGPRs: k-chunks 16*ks+8*h5 .. +7
    if (act) {
        int e = g0 + m;
        int nsrc = src[e];
        ndst = dst[e];
        dval = enorm[e];
#pragma unroll
        for (int ks = 0; ks < 4; ++ks) {
            const int cb = ks * 16 + h5 * 8;
            if constexpr (HB16)
                ags[ks] = *(const bf16x8*)(hb + (size_t)nsrc * FEAT + cb);
            else
                ags[ks] = hfrag_f32(h, nsrc, cb);
        }
    }

    // ---- Stage weights into LDS (once per block) ----
    {
        const bf16x8* gB1 = (const bf16x8*)B1;
        const bf16x8* gB2 = (const bf16x8*)B2;
        bf16x8* sB1 = (bf16x8*)B1s;
        bf16x8* sB2 = (bf16x8*)B2s;
#pragma unroll
        for (int it = 0; it < 8; ++it) {         // 3840 groups / 512 thr
            int g = it * 512 + tid;
            if (g < B1N_ELEMS / 8) sB1[g] = gB1[g];
        }
#pragma unroll
        for (int it = 0; it < 2; ++it) {         // 1024 groups / 512 thr
            int g = it * 512 + tid;
            sB2[g] = gB2[g];
        }
    }
    __syncthreads();
    if (!act) return;                            // after the only barrier

    // ---- Layer 1: H^T[128 x 32] = W1[128 x 240] . X^T[240 x 32] ----
    // acc1[nt1]: D rows = hidden n (nt1*32 + 8g + 4*h5 + i), col = edge m.
    fx16 acc1[4] = {};

    // RBF k-steps first (pure VALU+MFMA) -- slack for in-flight src gathers.
#pragma unroll
    for (int ks = 8; ks < 14; ++ks) {
        const int c0 = ks * 16 - 128 + h5 * 8;   // RBF col base, < 100
        float4 m0 = *(const float4*)(mu + c0);
        float4 m1 = *(const float4*)(mu + c0 + 4);
        const float d = dval;
        float t0 = m0.x - d, t1 = m0.y - d, t2 = m0.z - d, t3 = m0.w - d;
        float t4 = m1.x - d, t5 = m1.y - d, t6 = m1.z - d, t7 = m1.w - d;
        bf16x8 a = { (__bf16)__expf(-10.f * t0 * t0), (__bf16)__expf(-10.f * t1 * t1),
                     (__bf16)__expf(-10.f * t2 * t2), (__bf16)__expf(-10.f * t3 * t3),
                     (__bf16)__expf(-10.f * t4 * t4), (__bf16)__expf(-10.f * t5 * t5),
                     (__bf16)__expf(-10.f * t6 * t6), (__bf16)__expf(-10.f * t7 * t7) };
        const int base = ((ks * 2 + h5) * 128 + m) * 8;
#pragma unroll
        for (int nt1 = 0; nt1 < 4; ++nt1) {
            bf16x8 a1 = *(const bf16x8*)&B1s[base + nt1 * 256];
            acc1[nt1] = __builtin_amdgcn_mfma_f32_32x32x16_bf16(a1, a, acc1[nt1], 0, 0, 0);
        }
    }
    // ks = 14: cols 224..239; real only k < 228 -> h5==0, j<4.
    {
        float4 m7 = *(const float4*)(mu + 96);
        const float d = dval;
        const bool lo = (h5 == 0);
        const __bf16 zz = (__bf16)0.0f;
        float t0 = m7.x - d, t1 = m7.y - d, t2 = m7.z - d, t3 = m7.w - d;
        bf16x8 a = { lo ? (__bf16)__expf(-10.f * t0 * t0) : zz,
                     lo ? (__bf16)__expf(-10.f * t1 * t1) : zz,
                     lo ? (__bf16)__expf(-10.f * t2 * t2) : zz,
                     lo ? (__bf16)__expf(-10.f * t3 * t3) : zz,
                     zz, zz, zz, zz };
        const int base = ((14 * 2 + h5) * 128 + m) * 8;
#pragma unroll
        for (int nt1 = 0; nt1 < 4; ++nt1) {
            bf16x8 a1 = *(const bf16x8*)&B1s[base + nt1 * 256];
            acc1[nt1] = __builtin_amdgcn_mfma_f32_32x32x16_bf16(a1, a, acc1[nt1], 0, 0, 0);
        }
    }
    // ks = 0..3: src features (in registers since before staging)
#pragma unroll
    for (int ks = 0; ks < 4; ++ks) {
        const int base = ((ks * 2 + h5) * 128 + m) * 8;
#pragma unroll
        for (int nt1 = 0; nt1 < 4; ++nt1) {
            bf16x8 a1 = *(const bf16x8*)&B1s[base + nt1 * 256];
            acc1[nt1] = __builtin_amdgcn_mfma_f32_32x32x16_bf16(a1, ags[ks], acc1[nt1], 0, 0, 0);
        }
    }
    // dst gathers into the SAME registers (ags dead after ks=3 consume)
#pragma unroll
    for (int ks = 0; ks < 4; ++ks) {
        const int cb = ks * 16 + h5 * 8;
        if constexpr (HB16)
            ags[ks] = *(const bf16x8*)(hb + (size_t)ndst * FEAT + cb);
        else
            ags[ks] = hfrag_f32(h, ndst, cb);
    }
    // ks = 4..7: dst features
#pragma unroll
    for (int ks = 4; ks < 8; ++ks) {
        const int base = ((ks * 2 + h5) * 128 + m) * 8;
#pragma unroll
        for (int nt1 = 0; nt1 < 4; ++nt1) {
            bf16x8 a1 = *(const bf16x8*)&B1s[base + nt1 * 256];
            acc1[nt1] = __builtin_amdgcn_mfma_f32_32x32x16_bf16(a1, ags[ks - 4], acc1[nt1], 0, 0, 0);
        }
    }

    // ---- Epilogue: SiLU + layer 2, fully lane-local (rho absorbed the
    // transpose into the W2 pack). For k-step s = nt1*2 + t, the lane's
    // B-fragment is just acc1[nt1] elements 8t..8t+7, silu'd and packed.
    // O^T[64 x 32] = W2[64 x 128] . H^T[128 x 32]; no LDS, no barrier.
    fx16 acc2[2] = {};
#pragma unroll
    for (int nt1 = 0; nt1 < 4; ++nt1) {
        uint32_t P[8];
#pragma unroll
        for (int gp = 0; gp < 8; ++gp)
            P[gp] = pkbf16(silu(acc1[nt1][2 * gp]), silu(acc1[nt1][2 * gp + 1]));
#pragma unroll
        for (int t = 0; t < 2; ++t) {           // k-step s = nt1*2 + t
            const int s = nt1 * 2 + t;
            union { uint32_t u[4]; bf16x8 v; } uu;
            uu.u[0] = P[4 * t + 0]; uu.u[1] = P[4 * t + 1];
            uu.u[2] = P[4 * t + 2]; uu.u[3] = P[4 * t + 3];
            const int base2 = ((s * 2 + h5) * 64 + m) * 8;
#pragma unroll
            for (int n2t = 0; n2t < 2; ++n2t) {
                bf16x8 a2 = *(const bf16x8*)&B2s[base2 + n2t * 256];
                acc2[n2t] = __builtin_amdgcn_mfma_f32_32x32x16_bf16(a2, uu.v, acc2[n2t], 0, 0, 0);
            }
        }
    }

    // ---- Store: lane owns row (g0+m); cols n2 = n2t*32 + 8g + 4*h5 + 0..3.
    float* orow = out + (size_t)(g0 + m) * 64 + h5 * 4;
#pragma unroll
    for (int n2t = 0; n2t < 2; ++n2t)
#pragma unroll
        for (int g = 0; g < 4; ++g) {
            float4 st = { acc2[n2t][4 * g + 0], acc2[n2t][4 * g + 1],
                          acc2[n2t][4 * g + 2], acc2[n2t][4 * g + 3] };
            *(float4*)(orow + n2t * 32 + g * 8) = st;
        }
}

extern "C" void kernel_launch(void* const* d_in, const int* in_sizes, int n_in,
                              void* d_out, int out_size, void* d_ws, size_t ws_size,
                              hipStream_t stream) {
    const float* h   = (const float*)d_in[0];
    const int*   src = (const int*)d_in[1];
    const int*   dst = (const int*)d_in[2];
    const float* en  = (const float*)d_in[3];
    const float* mu  = (const float*)d_in[4];
    const float* W1  = (const float*)d_in[5];
    const float* W2  = (const float*)d_in[6];

    __bf16* B1 = (__bf16*)d_ws;                            // 61440 B
    __bf16* B2 = (__bf16*)((char*)d_ws + 61440);           // 16384 B
    __bf16* HB = (__bf16*)((char*)d_ws + 77824);           // 6.4 MB

    const size_t ws_needed = 77824 + (size_t)HN8 * 8 * sizeof(__bf16);
    const bool   use_hb    = ws_size >= ws_needed;

    pack_w<<<(B1N_ELEMS + B2N_ELEMS) / 256, 256, 0, stream>>>(W1, W2, B1, B2);

    const int E = in_sizes[1];                 // 800000
    const int nblocks = (E + BEDGES - 1) / BEDGES;   // 3125

    if (use_hb) {
        pack_h<<<(HN8 + 255) / 256, 256, 0, stream>>>(h, HB);
        edges_fused<true><<<nblocks, 512, 0, stream>>>(h, HB, src, dst, en, mu, B1, B2, (float*)d_out, E);
    } else {
        edges_fused<false><<<nblocks, 512, 0, stream>>>(h, nullptr, src, dst, en, mu, B1, B2, (float*)d_out, E);
    }
}